// Round 1
// 598.379 us; speedup vs baseline: 1.1242x; 1.1242x over previous
//
#include <hip/hip_runtime.h>
#include <cstdint>
#include <cstddef>

#define BB 8
#define SS 1024
#define HH 768
#define TT 8
#define DII 64
#define HIDD 128
#define KSP 8
#define NHEADS 2
#define NNODES 9
#define GDIM 256   // NHEADS*HIDD
#define CDIM 1024  // TT*2*DII == HH+GDIM
#define DAUGP 96   // 64 rope + 16 gauss + 16 zero pad (3 x 32-k MFMA slabs)
#define NEGV 1e12f

using bf16x8 = __attribute__((ext_vector_type(8))) __bf16;
using f32x4  = __attribute__((ext_vector_type(4))) float;

static __device__ inline unsigned short f2bf(float x) {
  union { float f; unsigned u; } v; v.f = x;
  unsigned r = v.u + 0x7fff + ((v.u >> 16) & 1);
  return (unsigned short)(r >> 16);
}

// ---------------- kc1: hidden fp32 -> bf16 (row-major [8192][768]) ---------------
__global__ void kc1_cvt_hidden(const float* __restrict__ hidden, unsigned short* __restrict__ hbf) {
  int idx = blockIdx.x * 256 + threadIdx.x;          // n/4 threads
  float4 v = *(const float4*)(hidden + (size_t)idx * 4);
  ushort4 o; o.x = f2bf(v.x); o.y = f2bf(v.y); o.z = f2bf(v.z); o.w = f2bf(v.w);
  *(ushort4*)(hbf + (size_t)idx * 4) = o;
}

// ---------------- kc2: dense_W[0:768][1024] -> WtopT[1024][768] bf16 -------------
__global__ void kc2_cvt_wtop(const float* __restrict__ dense_W, unsigned short* __restrict__ WtopT) {
  __shared__ float t[32][33];
  int k0 = blockIdx.x * 32, n0 = blockIdx.y * 32;
  int tid = threadIdx.x;
  int r = tid >> 3, c4 = (tid & 7) * 4;
  float4 v = *(const float4*)&dense_W[(size_t)(k0 + r) * CDIM + n0 + c4];
  t[r][c4 + 0] = v.x; t[r][c4 + 1] = v.y; t[r][c4 + 2] = v.z; t[r][c4 + 3] = v.w;
  __syncthreads();
  int ro = tid >> 3, co4 = (tid & 7) * 4;
  ushort4 o;
  o.x = f2bf(t[co4 + 0][ro]); o.y = f2bf(t[co4 + 1][ro]);
  o.z = f2bf(t[co4 + 2][ro]); o.w = f2bf(t[co4 + 3][ro]);
  *(ushort4*)&WtopT[(size_t)(n0 + ro) * HH + k0 + co4] = o;
}

// ---------------- k1a: cover + span means ----------------------------------------
// Span length is always <= 16 (length in [1,15], inclusive span). Fixed 16-trip
// loop with clamped addresses -> 16 independent loads in flight (latency fix).
__global__ void k1a_spans(const float* __restrict__ hidden, const int* __restrict__ spans,
                          float* __restrict__ nodes, float* __restrict__ cover) {
  int b = blockIdx.x, tid = threadIdx.x;
  __shared__ int sp[KSP * 3];
  if (tid < KSP * 3) sp[tid] = spans[b * KSP * 3 + tid];
  __syncthreads();
  for (int s = tid; s < SS; s += 256) {
    float c = 0.f;
    #pragma unroll
    for (int k = 0; k < KSP; k++)
      c += (s >= sp[k * 3] && s <= sp[k * 3 + 1]) ? 1.f : 0.f;
    cover[b * SS + s] = c;
  }
  const float* hb = hidden + (size_t)b * SS * HH;
  for (int k = 0; k < KSP; k++) {
    int st = sp[k * 3], en = sp[k * 3 + 1];
    float inv = 1.f / (float)(en - st + 1);
    #pragma unroll
    for (int ci = 0; ci < 3; ci++) {
      int c = tid + ci * 256;
      float a = 0.f;
      #pragma unroll
      for (int j = 0; j < 16; j++) {
        int s = st + j;
        int sc = (s <= en) ? s : en;          // clamp: address always valid
        float v = hb[(size_t)sc * HH + c];    // unconditional load -> pipelines
        a += (s <= en) ? v : 0.f;
      }
      nodes[((size_t)b * NNODES + (k + 1)) * HH + c] = a * inv;
    }
  }
}

// ---------------- k1b/k1c: global mean (2-stage) ---------------------------------
__global__ void k1b_partial(const float* __restrict__ hidden, float* __restrict__ part) {
  int z = blockIdx.x, b = blockIdx.y, tid = threadIdx.x;
  const float* hb = hidden + (size_t)b * SS * HH;
  #pragma unroll
  for (int j = 0; j < 3; j++) {
    int c = tid + j * 256;
    float acc = 0.f;
    #pragma unroll 8
    for (int r = z * 64; r < z * 64 + 64; r++) acc += hb[(size_t)r * HH + c];
    part[((size_t)b * 16 + z) * HH + c] = acc;
  }
}
__global__ void k1c_reduce(const float* __restrict__ part, float* __restrict__ nodes) {
  int b = blockIdx.x, tid = threadIdx.x;
  #pragma unroll
  for (int j = 0; j < 3; j++) {
    int c = tid + j * 256;
    float s = 0.f;
    #pragma unroll
    for (int z = 0; z < 16; z++) s += part[((size_t)b * 16 + z) * HH + c];
    nodes[(size_t)b * NNODES * HH + c] = s / (float)SS;
  }
}

// ---------------- k2: two GAT layers + LN -> enh ---------------------------------
// GEMM phases restructured: float4 LDS broadcasts of node operand (4x fewer LDS
// instructions) + 4 W loads per d-group + unroll 2 -> 8 global loads in flight.
__global__ __launch_bounds__(256) void k2_gat(
    const float* __restrict__ nodes_g, const int* __restrict__ spans,
    const float* __restrict__ W1, const float* __restrict__ a_src1,
    const float* __restrict__ a_dst1, const float* __restrict__ b1,
    const float* __restrict__ ln_g, const float* __restrict__ ln_b,
    const float* __restrict__ W2, const float* __restrict__ a_src2,
    const float* __restrict__ a_dst2, const float* __restrict__ b2,
    float* __restrict__ enhg) {
  int b = blockIdx.x, tid = threadIdx.x;
  __shared__ __align__(16) float nod[NNODES * HH];
  __shared__ __align__(16) float hbuf[NNODES * GDIM];
  __shared__ __align__(16) float gbuf[NNODES * GDIM];
  __shared__ float asrc[NNODES * NHEADS], adst[NNODES * NHEADS];
  __shared__ float adjm[NNODES * NNODES];
  __shared__ float attn[NNODES * NNODES * NHEADS];
  __shared__ float mu_s[NNODES], rs_s[NNODES];
  __shared__ int sp[KSP * 3];
  if (tid < KSP * 3) sp[tid] = spans[b * KSP * 3 + tid];
  for (int i = tid; i < NNODES * HH; i += 256)
    nod[i] = nodes_g[(size_t)b * NNODES * HH + i];
  __syncthreads();
  {
    float acc[NNODES];
    #pragma unroll
    for (int n = 0; n < NNODES; n++) acc[n] = 0.f;
    #pragma unroll 2
    for (int d0 = 0; d0 < HH; d0 += 4) {
      float4 nv[NNODES];
      #pragma unroll
      for (int n = 0; n < NNODES; n++) nv[n] = *(const float4*)&nod[n * HH + d0];
      float w0 = W1[(size_t)(d0 + 0) * GDIM + tid];
      float w1 = W1[(size_t)(d0 + 1) * GDIM + tid];
      float w2 = W1[(size_t)(d0 + 2) * GDIM + tid];
      float w3 = W1[(size_t)(d0 + 3) * GDIM + tid];
      #pragma unroll
      for (int n = 0; n < NNODES; n++)
        acc[n] += nv[n].x * w0 + nv[n].y * w1 + nv[n].z * w2 + nv[n].w * w3;
    }
    #pragma unroll
    for (int n = 0; n < NNODES; n++) hbuf[n * GDIM + tid] = acc[n];
  }
  if (tid < NNODES * NNODES) {
    int i = tid / NNODES, j = tid % NNODES;
    float a = (i == j) ? 1.f : 0.f;
    if (i > 0 && j == 0) a += 1.f;
    if (i == 0 && j > 0) a += 1.f;
    if (i > 0 && j > 0 && i != j) {
      int x = j - 1, y = i - 1;
      int sx = sp[x * 3], ex = sp[x * 3 + 1], sy = sp[y * 3], ey = sp[y * 3 + 1];
      bool same = (sx == sy) && (ex == ey);
      if (sx <= sy && ey <= ex && !same) a += 2.f;
    }
    adjm[tid] = a;
  }
  __syncthreads();
  if (tid < NNODES * NHEADS) {
    int n = tid >> 1, hd = tid & 1;
    float sa = 0.f, sd = 0.f;
    #pragma unroll 8
    for (int f = 0; f < HIDD; f++) {
      float v = hbuf[n * GDIM + hd * HIDD + f];
      sa += v * a_src1[hd * HIDD + f];
      sd += v * a_dst1[hd * HIDD + f];
    }
    asrc[tid] = sa; adst[tid] = sd;
  }
  __syncthreads();
  if (tid < NNODES * NHEADS) {
    int d = tid >> 1, hd = tid & 1;
    float sc[NNODES]; float mx = -1e30f;
    for (int s2 = 0; s2 < NNODES; s2++) {
      float a = adjm[d * NNODES + s2]; float v;
      if (a > 0.f) {
        float e = adst[d * 2 + hd] + asrc[s2 * 2 + hd];
        e = (e > 0.f) ? e : 0.2f * e;
        v = e + __logf(a);
      } else v = -1e30f;
      sc[s2] = v; mx = fmaxf(mx, v);
    }
    float ssum = 0.f;
    for (int s2 = 0; s2 < NNODES; s2++) { float ex = __expf(sc[s2] - mx); sc[s2] = ex; ssum += ex; }
    float inv = 1.f / ssum;
    for (int s2 = 0; s2 < NNODES; s2++) attn[(d * NNODES + s2) * NHEADS + hd] = sc[s2] * inv;
  }
  __syncthreads();
  {
    int hd = tid >> 7;
    float bb = b1[tid];
    for (int d = 0; d < NNODES; d++) {
      float acc = bb;
      #pragma unroll
      for (int s2 = 0; s2 < NNODES; s2++)
        acc += attn[(d * NNODES + s2) * NHEADS + hd] * hbuf[s2 * GDIM + tid];
      gbuf[d * GDIM + tid] = fmaxf(acc, 0.f);
    }
  }
  __syncthreads();
  if (tid < NNODES) {
    float s1 = 0.f, s2v = 0.f;
    #pragma unroll 8
    for (int o = 0; o < GDIM; o++) { float v = gbuf[tid * GDIM + o]; s1 += v; s2v += v * v; }
    float mu = s1 / (float)GDIM;
    float var = s2v / (float)GDIM - mu * mu;
    mu_s[tid] = mu; rs_s[tid] = rsqrtf(var + 1e-5f);
  }
  __syncthreads();
  {
    float g = ln_g[tid], bt = ln_b[tid];
    for (int d = 0; d < NNODES; d++)
      gbuf[d * GDIM + tid] = (gbuf[d * GDIM + tid] - mu_s[d]) * rs_s[d] * g + bt;
  }
  __syncthreads();
  {
    float acc[NNODES];
    #pragma unroll
    for (int n = 0; n < NNODES; n++) acc[n] = 0.f;
    #pragma unroll 2
    for (int d0 = 0; d0 < GDIM; d0 += 4) {
      float4 nv[NNODES];
      #pragma unroll
      for (int n = 0; n < NNODES; n++) nv[n] = *(const float4*)&gbuf[n * GDIM + d0];
      float w0 = W2[(size_t)(d0 + 0) * GDIM + tid];
      float w1 = W2[(size_t)(d0 + 1) * GDIM + tid];
      float w2 = W2[(size_t)(d0 + 2) * GDIM + tid];
      float w3 = W2[(size_t)(d0 + 3) * GDIM + tid];
      #pragma unroll
      for (int n = 0; n < NNODES; n++)
        acc[n] += nv[n].x * w0 + nv[n].y * w1 + nv[n].z * w2 + nv[n].w * w3;
    }
    #pragma unroll
    for (int n = 0; n < NNODES; n++) hbuf[n * GDIM + tid] = acc[n];
  }
  __syncthreads();
  if (tid < NNODES * NHEADS) {
    int n = tid >> 1, hd = tid & 1;
    float sa = 0.f, sd = 0.f;
    #pragma unroll 8
    for (int f = 0; f < HIDD; f++) {
      float v = hbuf[n * GDIM + hd * HIDD + f];
      sa += v * a_src2[hd * HIDD + f];
      sd += v * a_dst2[hd * HIDD + f];
    }
    asrc[tid] = sa; adst[tid] = sd;
  }
  __syncthreads();
  if (tid < NNODES * NHEADS) {
    int d = tid >> 1, hd = tid & 1;
    float sc[NNODES]; float mx = -1e30f;
    for (int s2 = 0; s2 < NNODES; s2++) {
      float a = adjm[d * NNODES + s2]; float v;
      if (a > 0.f) {
        float e = adst[d * 2 + hd] + asrc[s2 * 2 + hd];
        e = (e > 0.f) ? e : 0.2f * e;
        v = e + __logf(a);
      } else v = -1e30f;
      sc[s2] = v; mx = fmaxf(mx, v);
    }
    float ssum = 0.f;
    for (int s2 = 0; s2 < NNODES; s2++) { float ex = __expf(sc[s2] - mx); sc[s2] = ex; ssum += ex; }
    float inv = 1.f / ssum;
    for (int s2 = 0; s2 < NNODES; s2++) attn[(d * NNODES + s2) * NHEADS + hd] = sc[s2] * inv;
  }
  __syncthreads();
  {
    int hd = tid >> 7;
    float bb = b2[tid];
    float msum = 0.f;
    for (int d = 0; d < NNODES; d++) {
      float acc = bb;
      #pragma unroll
      for (int s2 = 0; s2 < NNODES; s2++)
        acc += attn[(d * NNODES + s2) * NHEADS + hd] * hbuf[s2 * GDIM + tid];
      msum += fmaxf(acc, 0.f);
    }
    enhg[b * GDIM + tid] = msum / 9.f;
  }
}

// ---------------- k2b: E2 = enh @ dense_W[768:1024] ------------------------------
__global__ void k2b_e2(const float* __restrict__ enhg, const float* __restrict__ dense_W,
                       float* __restrict__ E2) {
  int b = blockIdx.y, tid = threadIdx.x;
  int o = blockIdx.x * 256 + tid;
  __shared__ __align__(16) float eh[GDIM];
  eh[tid] = enhg[b * GDIM + tid];
  __syncthreads();
  float acc = 0.f;
  #pragma unroll 2
  for (int d = 0; d < GDIM; d += 4) {
    float4 ev = *(const float4*)&eh[d];
    acc += ev.x * dense_W[(size_t)(HH + d + 0) * CDIM + o];
    acc += ev.y * dense_W[(size_t)(HH + d + 1) * CDIM + o];
    acc += ev.z * dense_W[(size_t)(HH + d + 2) * CDIM + o];
    acc += ev.w * dense_W[(size_t)(HH + d + 3) * CDIM + o];
  }
  E2[b * CDIM + o] = acc;
}

// ---------------- k3: qk = hidden @ Wtop (MFMA bf16) + cover*E2 + b --------------
__global__ __launch_bounds__(256) void k3_dense(
    const unsigned short* __restrict__ hbf, const unsigned short* __restrict__ WtopT,
    const float* __restrict__ dense_b, const float* __restrict__ cover,
    const float* __restrict__ E2, float* __restrict__ qk) {
  __shared__ unsigned short As[128 * 40];  // [m][kpad=40]
  __shared__ unsigned short Bs[128 * 40];  // [n][kpad=40]
  int tid = threadIdx.x;
  int n0 = blockIdx.x * 128, m0 = blockIdx.y * 128;
  int wave = tid >> 6, lane = tid & 63;
  int wr = wave >> 1, wc = wave & 1;
  int colL = lane & 15, quad = lane >> 4;
  f32x4 acc[4][4];
  #pragma unroll
  for (int i = 0; i < 4; i++)
    #pragma unroll
    for (int j = 0; j < 4; j++) { acc[i][j][0] = 0.f; acc[i][j][1] = 0.f; acc[i][j][2] = 0.f; acc[i][j][3] = 0.f; }
  for (int k0 = 0; k0 < HH; k0 += 32) {
    uint4 va[2], vb[2];
    #pragma unroll
    for (int it = 0; it < 2; it++) {
      int idx = tid + it * 256;           // 0..511
      int r = idx >> 2, seg = idx & 3;
      va[it] = *(const uint4*)(hbf + (size_t)(m0 + r) * HH + k0 + seg * 8);
      vb[it] = *(const uint4*)(WtopT + (size_t)(n0 + r) * HH + k0 + seg * 8);
    }
    __syncthreads();
    #pragma unroll
    for (int it = 0; it < 2; it++) {
      int idx = tid + it * 256;
      int r = idx >> 2, seg = idx & 3;
      *(uint4*)&As[r * 40 + seg * 8] = va[it];
      *(uint4*)&Bs[r * 40 + seg * 8] = vb[it];
    }
    __syncthreads();
    bf16x8 af[4], bf[4];
    #pragma unroll
    for (int tm = 0; tm < 4; tm++)
      af[tm] = *(const bf16x8*)&As[(wr * 64 + tm * 16 + colL) * 40 + quad * 8];
    #pragma unroll
    for (int tn = 0; tn < 4; tn++)
      bf[tn] = *(const bf16x8*)&Bs[(wc * 64 + tn * 16 + colL) * 40 + quad * 8];
    #pragma unroll
    for (int tm = 0; tm < 4; tm++)
      #pragma unroll
      for (int tn = 0; tn < 4; tn++)
        acc[tm][tn] = __builtin_amdgcn_mfma_f32_16x16x32_bf16(af[tm], bf[tn], acc[tm][tn], 0, 0, 0);
  }
  int b = m0 >> 10;
  #pragma unroll
  for (int tn = 0; tn < 4; tn++) {
    int col = n0 + wc * 64 + tn * 16 + colL;
    float e2 = E2[b * CDIM + col];
    float db = dense_b[col];
    #pragma unroll
    for (int tm = 0; tm < 4; tm++) {
      int rbase = m0 + wr * 64 + tm * 16 + quad * 4;
      #pragma unroll
      for (int r = 0; r < 4; r++) {
        int m = rbase + r;
        qk[(size_t)m * CDIM + col] = acc[tm][tn][r] + cover[m] * e2 + db;
      }
    }
  }
}

// ---------------- k4: RoPE + gauss -> Qa/Ka bf16 [bt][s][96] ---------------------
__global__ void k4_ropeaug(const float* __restrict__ qk, const int* __restrict__ spans,
                           const float* __restrict__ corr, const float* __restrict__ gc,
                           const float* __restrict__ gs, const float* __restrict__ gw,
                           unsigned short* __restrict__ Qa, unsigned short* __restrict__ Ka) {
  int tid = threadIdx.x;
  int g = tid >> 5, lane = tid & 31;
  int row = blockIdx.x * 8 + g;           // global (b,s) row
  int b = row >> 10, s = row & 1023;
  const float* qrow = qk + (size_t)row * CDIM;
  const float LOG1E4_32 = 0.28782313662425576f;  // ln(10000)/32
  #pragma unroll
  for (int it = 0; it < 8; it++) {
    int cbase = it * 128 + lane * 4;
    float4 v = *(const float4*)(qrow + cbase);
    int t = cbase >> 7;
    int d = cbase & 127;
    int dd = d & 63;
    int i0 = dd >> 1;
    float inv0 = __expf(-(float)i0 * LOG1E4_32);
    float inv1 = __expf(-(float)(i0 + 1) * LOG1E4_32);
    float s0, c0, s1, c1;
    __sincosf((float)s * inv0, &s0, &c0);
    __sincosf((float)s * inv1, &s1, &c1);
    float o0 = v.x * c0 - v.y * s0;
    float o1 = v.y * c0 + v.x * s0;
    float o2 = v.z * c1 - v.w * s1;
    float o3 = v.w * c1 + v.z * s1;
    ushort4 w; w.x = f2bf(o0); w.y = f2bf(o1); w.z = f2bf(o2); w.w = f2bf(o3);
    size_t base = ((size_t)(b * TT + t) * SS + s) * DAUGP;
    if (d < 64) *(ushort4*)(Qa + base + dd) = w;
    else        *(ushort4*)(Ka + base + dd) = w;
  }
  // gauss dims 64..79 and zero pad 80..95
  int j = lane & 15;
  int kp = j >> 1, c = j & 1;
  int st = spans[(b * KSP + kp) * 3 + 0];
  int en = spans[(b * KSP + kp) * 3 + 1];
  int et = spans[(b * KSP + kp) * 3 + 2];
  float sig = gs[c], wgt = gw[c], ce = gc[c];
  if (lane < 16) {
    float dx = ((float)(s - st) - ce) / sig;
    float e = wgt * __expf(-0.5f * dx * dx);
    #pragma unroll
    for (int t = 0; t < TT; t++) {
      size_t base = ((size_t)(b * TT + t) * SS + s) * DAUGP;
      Qa[base + 64 + j] = f2bf(corr[et * TT + t] * e);
      Qa[base + 80 + j] = 0;
    }
  } else {
    float dx = ((float)(s - en) - ce) / sig;
    unsigned short bv = f2bf(wgt * __expf(-0.5f * dx * dx));
    #pragma unroll
    for (int t = 0; t < TT; t++) {
      size_t base = ((size_t)(b * TT + t) * SS + s) * DAUGP;
      Ka[base + 64 + j] = bv;
      Ka[base + 80 + j] = 0;
    }
  }
}

// ---------------- k5: logits = Qa @ Ka^T (MFMA bf16) + mask ----------------------
__global__ __launch_bounds__(256) void k5_logits(
    const unsigned short* __restrict__ Qa, const unsigned short* __restrict__ Ka,
    const float* __restrict__ amask, float* __restrict__ out) {
  int bz = blockIdx.z; int b = bz >> 3;
  int n0 = blockIdx.x * 128, m0 = blockIdx.y * 128;
  int tid = threadIdx.x;
  if (n0 + 127 < m0) {
    // strictly below diagonal: write masked constant
    int r0 = tid >> 5, c4 = (tid & 31) * 4;
    float4 pv = *(const float4*)&amask[b * SS + n0 + c4];
    float4 o;
    o.x = (-(1.f - pv.x) * NEGV - NEGV) * 0.125f;
    o.y = (-(1.f - pv.y) * NEGV - NEGV) * 0.125f;
    o.z = (-(1.f - pv.z) * NEGV - NEGV) * 0.125f;
    o.w = (-(1.f - pv.w) * NEGV - NEGV) * 0.125f;
    for (int r = r0; r < 128; r += 8)
      *(float4*)&out[((size_t)bz * SS + m0 + r) * SS + n0 + c4] = o;
    return;
  }
  __shared__ unsigned short Qs[128 * 104];   // [m][kpad=104]
  __shared__ unsigned short Ks[128 * 104];   // [n][kpad=104]
  const unsigned short* Qrow = Qa + ((size_t)bz * SS + m0) * DAUGP;
  const unsigned short* Krow = Ka + ((size_t)bz * SS + n0) * DAUGP;
  #pragma unroll
  for (int it = 0; it < 6; it++) {
    int idx = tid + it * 256;                // 0..1535
    int r = idx / 12, seg = idx % 12;
    uint4 vq = *(const uint4*)(Qrow + (size_t)r * DAUGP + seg * 8);
    uint4 vk = *(const uint4*)(Krow + (size_t)r * DAUGP + seg * 8);
    *(uint4*)&Qs[r * 104 + seg * 8] = vq;
    *(uint4*)&Ks[r * 104 + seg * 8] = vk;
  }
  __syncthreads();
  int wave = tid >> 6, lane = tid & 63;
  int wr = wave >> 1, wc = wave & 1;
  int colL = lane & 15, quad = lane >> 4;
  f32x4 acc[4][4];
  #pragma unroll
  for (int i = 0; i < 4; i++)
    #pragma unroll
    for (int j = 0; j < 4; j++) { acc[i][j][0] = 0.f; acc[i][j][1] = 0.f; acc[i][j][2] = 0.f; acc[i][j][3] = 0.f; }
  #pragma unroll
  for (int ks = 0; ks < 3; ks++) {
    bf16x8 af[4], bf[4];
    #pragma unroll
    for (int tm = 0; tm < 4; tm++)
      af[tm] = *(const bf16x8*)&Qs[(wr * 64 + tm * 16 + colL) * 104 + ks * 32 + quad * 8];
    #pragma unroll
    for (int tn = 0; tn < 4; tn++)
      bf[tn] = *(const bf16x8*)&Ks[(wc * 64 + tn * 16 + colL) * 104 + ks * 32 + quad * 8];
    #pragma unroll
    for (int tm = 0; tm < 4; tm++)
      #pragma unroll
      for (int tn = 0; tn < 4; tn++)
        acc[tm][tn] = __builtin_amdgcn_mfma_f32_16x16x32_bf16(af[tm], bf[tn], acc[tm][tn], 0, 0, 0);
  }
  #pragma unroll
  for (int tn = 0; tn < 4; tn++) {
    int col = n0 + wc * 64 + tn * 16 + colL;
    float p = amask[b * SS + col];
    float negp = -(1.f - p) * NEGV;
    #pragma unroll
    for (int tm = 0; tm < 4; tm++) {
      int rbase = m0 + wr * 64 + tm * 16 + quad * 4;
      #pragma unroll
      for (int r = 0; r < 4; r++) {
        int m = rbase + r;
        float v = acc[tm][tn][r] * p + negp;
        if (col < m) v -= NEGV;
        out[((size_t)bz * SS + m) * SS + col] = v * 0.125f;
      }
    }
  }
}

extern "C" void kernel_launch(void* const* d_in, const int* in_sizes, int n_in,
                              void* d_out, int out_size, void* d_ws, size_t ws_size,
                              hipStream_t stream) {
  const float* hidden  = (const float*)d_in[0];
  const float* amask   = (const float*)d_in[1];
  const int*   spans   = (const int*)d_in[2];
  const float* W1      = (const float*)d_in[3];
  const float* a_src1  = (const float*)d_in[4];
  const float* a_dst1  = (const float*)d_in[5];
  const float* b1      = (const float*)d_in[6];
  const float* ln_g    = (const float*)d_in[7];
  const float* ln_b    = (const float*)d_in[8];
  const float* W2      = (const float*)d_in[9];
  const float* a_src2  = (const float*)d_in[10];
  const float* a_dst2  = (const float*)d_in[11];
  const float* b2      = (const float*)d_in[12];
  const float* dense_W = (const float*)d_in[13];
  const float* dense_b = (const float*)d_in[14];
  const float* gc      = (const float*)d_in[15];
  const float* gs      = (const float*)d_in[16];
  const float* gw      = (const float*)d_in[17];
  const float* corr    = (const float*)d_in[18];

  char* wsb = (char*)d_ws;
  float* qk            = (float*)wsb;                         wsb += (size_t)BB * SS * CDIM * 4;        // 33.5 MB
  unsigned short* hbf  = (unsigned short*)wsb;                wsb += (size_t)BB * SS * HH * 2;          // 12.6 MB
  unsigned short* WtopT= (unsigned short*)wsb;                wsb += (size_t)CDIM * HH * 2;             // 1.57 MB
  unsigned short* Qa   = (unsigned short*)wsb;                wsb += (size_t)BB * TT * SS * DAUGP * 2;  // 12.6 MB
  unsigned short* Ka   = (unsigned short*)wsb;                wsb += (size_t)BB * TT * SS * DAUGP * 2;  // 12.6 MB
  float* nodes         = (float*)wsb;                         wsb += (size_t)BB * NNODES * HH * 4;
  float* cover         = (float*)wsb;                         wsb += (size_t)BB * SS * 4;
  float* E2            = (float*)wsb;                         wsb += (size_t)BB * CDIM * 4;
  float* enhg          = (float*)wsb;                         wsb += (size_t)BB * GDIM * 4;
  float* part          = (float*)wsb;                         wsb += (size_t)BB * 16 * HH * 4;
  float* outp = (float*)d_out;

  kc1_cvt_hidden<<<(BB * SS * HH / 4) / 256, 256, 0, stream>>>(hidden, hbf);
  kc2_cvt_wtop<<<dim3(HH / 32, CDIM / 32), 256, 0, stream>>>(dense_W, WtopT);
  k1a_spans<<<BB, 256, 0, stream>>>(hidden, spans, nodes, cover);
  k1b_partial<<<dim3(16, BB), 256, 0, stream>>>(hidden, part);
  k1c_reduce<<<BB, 256, 0, stream>>>(part, nodes);
  k2_gat<<<BB, 256, 0, stream>>>(nodes, spans, W1, a_src1, a_dst1, b1, ln_g, ln_b,
                                 W2, a_src2, a_dst2, b2, enhg);
  k2b_e2<<<dim3(CDIM / 256, BB), 256, 0, stream>>>(enhg, dense_W, E2);
  k3_dense<<<dim3(CDIM / 128, (BB * SS) / 128), 256, 0, stream>>>(hbf, WtopT, dense_b,
                                                                  cover, E2, qk);
  k4_ropeaug<<<(BB * SS) / 8, 256, 0, stream>>>(qk, spans, corr, gc, gs, gw, Qa, Ka);
  k5_logits<<<dim3(8, 8, BB * TT), 256, 0, stream>>>(Qa, Ka, amask, outp);
}

// Round 2
// 559.948 us; speedup vs baseline: 1.2013x; 1.0686x over previous
//
#include <hip/hip_runtime.h>
#include <cstdint>
#include <cstddef>

#define BB 8
#define SS 1024
#define HH 768
#define TT 8
#define DII 64
#define HIDD 128
#define KSP 8
#define NHEADS 2
#define NNODES 9
#define GDIM 256   // NHEADS*HIDD
#define CDIM 1024  // TT*2*DII == HH+GDIM
#define DAUGP 96   // 64 rope + 16 gauss + 16 zero pad (3 x 32-k MFMA slabs)
#define NEGV 1e12f

using bf16x8 = __attribute__((ext_vector_type(8))) __bf16;
using f32x4  = __attribute__((ext_vector_type(4))) float;

static __device__ inline unsigned short f2bf(float x) {
  union { float f; unsigned u; } v; v.f = x;
  unsigned r = v.u + 0x7fff + ((v.u >> 16) & 1);
  return (unsigned short)(r >> 16);
}

// ------- kc1b: hidden fp32 -> bf16 AND 64-row partial column sums (fused) --------
__global__ void kc1b_cvt_partial(const float* __restrict__ hidden,
                                 unsigned short* __restrict__ hbf,
                                 float* __restrict__ part) {
  int z = blockIdx.x, b = blockIdx.y, tid = threadIdx.x;
  const float* hb = hidden + (size_t)b * SS * HH;
  unsigned short* ho = hbf + (size_t)b * SS * HH;
  #pragma unroll
  for (int j = 0; j < 3; j++) {
    int c = tid + j * 256;
    float acc = 0.f;
    #pragma unroll 8
    for (int r = z * 64; r < z * 64 + 64; r++) {
      float v = hb[(size_t)r * HH + c];
      ho[(size_t)r * HH + c] = f2bf(v);
      acc += v;
    }
    part[((size_t)b * 16 + z) * HH + c] = acc;
  }
}

// ---------------- kc2: dense_W[0:768][1024] -> WtopT[1024][768] bf16 -------------
__global__ void kc2_cvt_wtop(const float* __restrict__ dense_W, unsigned short* __restrict__ WtopT) {
  __shared__ float t[32][33];
  int k0 = blockIdx.x * 32, n0 = blockIdx.y * 32;
  int tid = threadIdx.x;
  int r = tid >> 3, c4 = (tid & 7) * 4;
  float4 v = *(const float4*)&dense_W[(size_t)(k0 + r) * CDIM + n0 + c4];
  t[r][c4 + 0] = v.x; t[r][c4 + 1] = v.y; t[r][c4 + 2] = v.z; t[r][c4 + 3] = v.w;
  __syncthreads();
  int ro = tid >> 3, co4 = (tid & 7) * 4;
  ushort4 o;
  o.x = f2bf(t[co4 + 0][ro]); o.y = f2bf(t[co4 + 1][ro]);
  o.z = f2bf(t[co4 + 2][ro]); o.w = f2bf(t[co4 + 3][ro]);
  *(ushort4*)&WtopT[(size_t)(n0 + ro) * HH + k0 + co4] = o;
}

// ---------------- k1a: cover + span means (one block per (span,batch)) -----------
// Span length <= 16 always: fixed 16-trip clamped loads -> all loads in flight.
__global__ void k1a_spans(const float* __restrict__ hidden, const int* __restrict__ spans,
                          float* __restrict__ nodes, float* __restrict__ cover) {
  int k = blockIdx.x, b = blockIdx.y, tid = threadIdx.x;
  __shared__ int sp[KSP * 3];
  if (tid < KSP * 3) sp[tid] = spans[b * KSP * 3 + tid];
  __syncthreads();
  if (tid < 128) {
    int s = k * 128 + tid;
    float c = 0.f;
    #pragma unroll
    for (int kk = 0; kk < KSP; kk++)
      c += (s >= sp[kk * 3] && s <= sp[kk * 3 + 1]) ? 1.f : 0.f;
    cover[b * SS + s] = c;
  }
  int st = sp[k * 3], en = sp[k * 3 + 1];
  float inv = 1.f / (float)(en - st + 1);
  const float* hb = hidden + (size_t)b * SS * HH;
  #pragma unroll
  for (int ci = 0; ci < 3; ci++) {
    int c = tid + ci * 256;
    float a = 0.f;
    #pragma unroll
    for (int j = 0; j < 16; j++) {
      int s = st + j;
      int sc = (s <= en) ? s : en;          // clamp: address always valid
      float v = hb[(size_t)sc * HH + c];    // unconditional load -> pipelines
      a += (s <= en) ? v : 0.f;
    }
    nodes[((size_t)b * NNODES + (k + 1)) * HH + c] = a * inv;
  }
}

// ---------------- k2: two GAT layers + LN -> enh (512 threads, d-split GEMMs) ----
// k1c folded into prologue (node 0 from part). GEMM phases split over 2 halves of
// the reduction dim -> half trip count, 2 waves/SIMD for latency hiding.
__global__ __launch_bounds__(512) void k2_gat(
    const float* __restrict__ part, const float* __restrict__ nodes_g,
    const int* __restrict__ spans,
    const float* __restrict__ W1, const float* __restrict__ a_src1,
    const float* __restrict__ a_dst1, const float* __restrict__ b1,
    const float* __restrict__ ln_g, const float* __restrict__ ln_b,
    const float* __restrict__ W2, const float* __restrict__ a_src2,
    const float* __restrict__ a_dst2, const float* __restrict__ b2,
    float* __restrict__ enhg) {
  int b = blockIdx.x, tid = threadIdx.x;
  __shared__ __align__(16) float nod[NNODES * HH];
  __shared__ __align__(16) float hbuf[NNODES * GDIM];
  __shared__ __align__(16) float gbuf[NNODES * GDIM];
  __shared__ __align__(16) float pbuf[2 * NNODES * GDIM];
  __shared__ float asrc[NNODES * NHEADS], adst[NNODES * NHEADS];
  __shared__ float adjm[NNODES * NNODES];
  __shared__ float attn[NNODES * NNODES * NHEADS];
  __shared__ float mu_s[NNODES], rs_s[NNODES];
  __shared__ int sp[KSP * 3];
  if (tid < KSP * 3) sp[tid] = spans[b * KSP * 3 + tid];
  // node 0 = global mean from 16 partials (was k1c)
  for (int c = tid; c < HH; c += 512) {
    float s = 0.f;
    #pragma unroll
    for (int z = 0; z < 16; z++) s += part[((size_t)b * 16 + z) * HH + c];
    nod[c] = s * (1.f / (float)SS);
  }
  for (int i = tid; i < (NNODES - 1) * HH; i += 512)
    nod[HH + i] = nodes_g[(size_t)b * NNODES * HH + HH + i];
  __syncthreads();
  { // layer-1 GEMM: half h covers d in [h*384, h*384+384)
    int col = tid & 255, h = tid >> 8;
    float acc[NNODES];
    #pragma unroll
    for (int n = 0; n < NNODES; n++) acc[n] = 0.f;
    int dlo = h * 384;
    #pragma unroll 2
    for (int d0 = dlo; d0 < dlo + 384; d0 += 4) {
      float4 nv[NNODES];
      #pragma unroll
      for (int n = 0; n < NNODES; n++) nv[n] = *(const float4*)&nod[n * HH + d0];
      float w0 = W1[(size_t)(d0 + 0) * GDIM + col];
      float w1 = W1[(size_t)(d0 + 1) * GDIM + col];
      float w2 = W1[(size_t)(d0 + 2) * GDIM + col];
      float w3 = W1[(size_t)(d0 + 3) * GDIM + col];
      #pragma unroll
      for (int n = 0; n < NNODES; n++)
        acc[n] += nv[n].x * w0 + nv[n].y * w1 + nv[n].z * w2 + nv[n].w * w3;
    }
    #pragma unroll
    for (int n = 0; n < NNODES; n++) pbuf[(h * NNODES + n) * GDIM + col] = acc[n];
  }
  __syncthreads();
  if (tid < GDIM) {                         // combine halves
    #pragma unroll
    for (int n = 0; n < NNODES; n++)
      hbuf[n * GDIM + tid] = pbuf[n * GDIM + tid] + pbuf[(NNODES + n) * GDIM + tid];
  } else if (tid < 256 + NNODES * NNODES) { // adjacency, concurrent thread range
    int q = tid - 256;
    int i = q / NNODES, j = q % NNODES;
    float a = (i == j) ? 1.f : 0.f;
    if (i > 0 && j == 0) a += 1.f;
    if (i == 0 && j > 0) a += 1.f;
    if (i > 0 && j > 0 && i != j) {
      int x = j - 1, y = i - 1;
      int sx = sp[x * 3], ex = sp[x * 3 + 1], sy = sp[y * 3], ey = sp[y * 3 + 1];
      bool same = (sx == sy) && (ex == ey);
      if (sx <= sy && ey <= ex && !same) a += 2.f;
    }
    adjm[q] = a;
  }
  __syncthreads();
  if (tid < NNODES * NHEADS) {
    int n = tid >> 1, hd = tid & 1;
    float sa = 0.f, sd = 0.f;
    #pragma unroll 8
    for (int f = 0; f < HIDD; f++) {
      float v = hbuf[n * GDIM + hd * HIDD + f];
      sa += v * a_src1[hd * HIDD + f];
      sd += v * a_dst1[hd * HIDD + f];
    }
    asrc[tid] = sa; adst[tid] = sd;
  }
  __syncthreads();
  if (tid < NNODES * NHEADS) {
    int d = tid >> 1, hd = tid & 1;
    float sc[NNODES]; float mx = -1e30f;
    for (int s2 = 0; s2 < NNODES; s2++) {
      float a = adjm[d * NNODES + s2]; float v;
      if (a > 0.f) {
        float e = adst[d * 2 + hd] + asrc[s2 * 2 + hd];
        e = (e > 0.f) ? e : 0.2f * e;
        v = e + __logf(a);
      } else v = -1e30f;
      sc[s2] = v; mx = fmaxf(mx, v);
    }
    float ssum = 0.f;
    for (int s2 = 0; s2 < NNODES; s2++) { float ex = __expf(sc[s2] - mx); sc[s2] = ex; ssum += ex; }
    float inv = 1.f / ssum;
    for (int s2 = 0; s2 < NNODES; s2++) attn[(d * NNODES + s2) * NHEADS + hd] = sc[s2] * inv;
  }
  __syncthreads();
  if (tid < 256) {
    int hd = tid >> 7;
    float bbv = b1[tid];
    for (int d = 0; d < NNODES; d++) {
      float acc = bbv;
      #pragma unroll
      for (int s2 = 0; s2 < NNODES; s2++)
        acc += attn[(d * NNODES + s2) * NHEADS + hd] * hbuf[s2 * GDIM + tid];
      gbuf[d * GDIM + tid] = fmaxf(acc, 0.f);
    }
  }
  __syncthreads();
  if (tid < NNODES) {
    float s1 = 0.f, s2v = 0.f;
    #pragma unroll 8
    for (int o = 0; o < GDIM; o++) { float v = gbuf[tid * GDIM + o]; s1 += v; s2v += v * v; }
    float mu = s1 / (float)GDIM;
    float var = s2v / (float)GDIM - mu * mu;
    mu_s[tid] = mu; rs_s[tid] = rsqrtf(var + 1e-5f);
  }
  __syncthreads();
  if (tid < 256) {
    float g = ln_g[tid], bt = ln_b[tid];
    for (int d = 0; d < NNODES; d++)
      gbuf[d * GDIM + tid] = (gbuf[d * GDIM + tid] - mu_s[d]) * rs_s[d] * g + bt;
  }
  __syncthreads();
  { // layer-2 GEMM: half h covers d in [h*128, h*128+128)
    int col = tid & 255, h = tid >> 8;
    float acc[NNODES];
    #pragma unroll
    for (int n = 0; n < NNODES; n++) acc[n] = 0.f;
    int dlo = h * 128;
    #pragma unroll 2
    for (int d0 = dlo; d0 < dlo + 128; d0 += 4) {
      float4 nv[NNODES];
      #pragma unroll
      for (int n = 0; n < NNODES; n++) nv[n] = *(const float4*)&gbuf[n * GDIM + d0];
      float w0 = W2[(size_t)(d0 + 0) * GDIM + col];
      float w1 = W2[(size_t)(d0 + 1) * GDIM + col];
      float w2 = W2[(size_t)(d0 + 2) * GDIM + col];
      float w3 = W2[(size_t)(d0 + 3) * GDIM + col];
      #pragma unroll
      for (int n = 0; n < NNODES; n++)
        acc[n] += nv[n].x * w0 + nv[n].y * w1 + nv[n].z * w2 + nv[n].w * w3;
    }
    #pragma unroll
    for (int n = 0; n < NNODES; n++) pbuf[(h * NNODES + n) * GDIM + col] = acc[n];
  }
  __syncthreads();
  if (tid < GDIM) {
    #pragma unroll
    for (int n = 0; n < NNODES; n++)
      hbuf[n * GDIM + tid] = pbuf[n * GDIM + tid] + pbuf[(NNODES + n) * GDIM + tid];
  }
  __syncthreads();
  if (tid < NNODES * NHEADS) {
    int n = tid >> 1, hd = tid & 1;
    float sa = 0.f, sd = 0.f;
    #pragma unroll 8
    for (int f = 0; f < HIDD; f++) {
      float v = hbuf[n * GDIM + hd * HIDD + f];
      sa += v * a_src2[hd * HIDD + f];
      sd += v * a_dst2[hd * HIDD + f];
    }
    asrc[tid] = sa; adst[tid] = sd;
  }
  __syncthreads();
  if (tid < NNODES * NHEADS) {
    int d = tid >> 1, hd = tid & 1;
    float sc[NNODES]; float mx = -1e30f;
    for (int s2 = 0; s2 < NNODES; s2++) {
      float a = adjm[d * NNODES + s2]; float v;
      if (a > 0.f) {
        float e = adst[d * 2 + hd] + asrc[s2 * 2 + hd];
        e = (e > 0.f) ? e : 0.2f * e;
        v = e + __logf(a);
      } else v = -1e30f;
      sc[s2] = v; mx = fmaxf(mx, v);
    }
    float ssum = 0.f;
    for (int s2 = 0; s2 < NNODES; s2++) { float ex = __expf(sc[s2] - mx); sc[s2] = ex; ssum += ex; }
    float inv = 1.f / ssum;
    for (int s2 = 0; s2 < NNODES; s2++) attn[(d * NNODES + s2) * NHEADS + hd] = sc[s2] * inv;
  }
  __syncthreads();
  if (tid < 256) {
    int hd = tid >> 7;
    float bbv = b2[tid];
    float msum = 0.f;
    for (int d = 0; d < NNODES; d++) {
      float acc = bbv;
      #pragma unroll
      for (int s2 = 0; s2 < NNODES; s2++)
        acc += attn[(d * NNODES + s2) * NHEADS + hd] * hbuf[s2 * GDIM + tid];
      msum += fmaxf(acc, 0.f);
    }
    enhg[b * GDIM + tid] = msum / 9.f;
  }
}

// ---------------- k2b: E2 = enh @ dense_W[768:1024] ------------------------------
__global__ void k2b_e2(const float* __restrict__ enhg, const float* __restrict__ dense_W,
                       float* __restrict__ E2) {
  int b = blockIdx.y, tid = threadIdx.x;
  int o = blockIdx.x * 256 + tid;
  __shared__ __align__(16) float eh[GDIM];
  eh[tid] = enhg[b * GDIM + tid];
  __syncthreads();
  float acc = 0.f;
  #pragma unroll 2
  for (int d = 0; d < GDIM; d += 4) {
    float4 ev = *(const float4*)&eh[d];
    acc += ev.x * dense_W[(size_t)(HH + d + 0) * CDIM + o];
    acc += ev.y * dense_W[(size_t)(HH + d + 1) * CDIM + o];
    acc += ev.z * dense_W[(size_t)(HH + d + 2) * CDIM + o];
    acc += ev.w * dense_W[(size_t)(HH + d + 3) * CDIM + o];
  }
  E2[b * CDIM + o] = acc;
}

// ------- k3: qk = hidden @ Wtop + cover*E2 + b, RoPE fused -> Qa/Ka bf16 ---------
// RoPE partner value (col^1) fetched via __shfl_xor(.,1): adjacent colL lanes hold
// adjacent columns. Eliminates the 33.5MB qk round-trip and k4's rope pass.
__global__ __launch_bounds__(256) void k3_dense(
    const unsigned short* __restrict__ hbf, const unsigned short* __restrict__ WtopT,
    const float* __restrict__ dense_b, const float* __restrict__ cover,
    const float* __restrict__ E2,
    unsigned short* __restrict__ Qa, unsigned short* __restrict__ Ka) {
  __shared__ unsigned short As[128 * 40];  // [m][kpad=40]
  __shared__ unsigned short Bs[128 * 40];  // [n][kpad=40]
  int tid = threadIdx.x;
  int n0 = blockIdx.x * 128, m0 = blockIdx.y * 128;
  int wave = tid >> 6, lane = tid & 63;
  int wr = wave >> 1, wc = wave & 1;
  int colL = lane & 15, quad = lane >> 4;
  f32x4 acc[4][4];
  #pragma unroll
  for (int i = 0; i < 4; i++)
    #pragma unroll
    for (int j = 0; j < 4; j++) { acc[i][j][0] = 0.f; acc[i][j][1] = 0.f; acc[i][j][2] = 0.f; acc[i][j][3] = 0.f; }
  for (int k0 = 0; k0 < HH; k0 += 32) {
    uint4 va[2], vb[2];
    #pragma unroll
    for (int it = 0; it < 2; it++) {
      int idx = tid + it * 256;           // 0..511
      int r = idx >> 2, seg = idx & 3;
      va[it] = *(const uint4*)(hbf + (size_t)(m0 + r) * HH + k0 + seg * 8);
      vb[it] = *(const uint4*)(WtopT + (size_t)(n0 + r) * HH + k0 + seg * 8);
    }
    __syncthreads();
    #pragma unroll
    for (int it = 0; it < 2; it++) {
      int idx = tid + it * 256;
      int r = idx >> 2, seg = idx & 3;
      *(uint4*)&As[r * 40 + seg * 8] = va[it];
      *(uint4*)&Bs[r * 40 + seg * 8] = vb[it];
    }
    __syncthreads();
    bf16x8 af[4], bf[4];
    #pragma unroll
    for (int tm = 0; tm < 4; tm++)
      af[tm] = *(const bf16x8*)&As[(wr * 64 + tm * 16 + colL) * 40 + quad * 8];
    #pragma unroll
    for (int tn = 0; tn < 4; tn++)
      bf[tn] = *(const bf16x8*)&Bs[(wc * 64 + tn * 16 + colL) * 40 + quad * 8];
    #pragma unroll
    for (int tm = 0; tm < 4; tm++)
      #pragma unroll
      for (int tn = 0; tn < 4; tn++)
        acc[tm][tn] = __builtin_amdgcn_mfma_f32_16x16x32_bf16(af[tm], bf[tn], acc[tm][tn], 0, 0, 0);
  }
  int b = m0 >> 10;
  const float LOG1E4_32 = 0.28782313662425576f;  // ln(10000)/32
  // col = n0 + wc*64 + tn*16 + colL; d = col&127 = wc*64 + tn*16 + colL
  // -> wc==0 is Q-half, wc==1 is K-half; dd = tn*16+colL identical for both.
  unsigned short* __restrict__ dst = (wc == 0) ? Qa : Ka;
  #pragma unroll
  for (int tn = 0; tn < 4; tn++) {
    int col = n0 + wc * 64 + tn * 16 + colL;
    float e2 = E2[b * CDIM + col];
    float db = dense_b[col];
    int t = col >> 7;
    int dd = tn * 16 + colL;
    int i0 = dd >> 1;
    float inv = __expf(-(float)i0 * LOG1E4_32);
    float sgn = (dd & 1) ? 1.f : -1.f;
    size_t tbase = (size_t)(b * TT + t) * SS;
    #pragma unroll
    for (int tm = 0; tm < 4; tm++) {
      int rbase = m0 + wr * 64 + tm * 16 + quad * 4;
      #pragma unroll
      for (int r = 0; r < 4; r++) {
        int m = rbase + r;
        int s = m & 1023;
        float w = acc[tm][tn][r] + cover[m] * e2 + db;
        float p = __shfl_xor(w, 1, 64);
        float sn, cs;
        __sincosf((float)s * inv, &sn, &cs);
        float o = w * cs + sgn * p * sn;
        dst[(tbase + s) * DAUGP + dd] = f2bf(o);
      }
    }
  }
}

// ---------------- k4g: gauss dims 64..79 + zero pad 80..95 -----------------------
__global__ void k4g_gauss(const int* __restrict__ spans, const float* __restrict__ corr,
                          const float* __restrict__ gc, const float* __restrict__ gs,
                          const float* __restrict__ gw,
                          unsigned short* __restrict__ Qa, unsigned short* __restrict__ Ka) {
  int tid = threadIdx.x;
  int g = tid >> 5, lane = tid & 31;
  int row = blockIdx.x * 8 + g;           // global (b,s) row
  int b = row >> 10, s = row & 1023;
  int j = lane & 15;
  int kp = j >> 1, c = j & 1;
  int st = spans[(b * KSP + kp) * 3 + 0];
  int en = spans[(b * KSP + kp) * 3 + 1];
  int et = spans[(b * KSP + kp) * 3 + 2];
  float sig = gs[c], wgt = gw[c], ce = gc[c];
  if (lane < 16) {
    float dx = ((float)(s - st) - ce) / sig;
    float e = wgt * __expf(-0.5f * dx * dx);
    #pragma unroll
    for (int t = 0; t < TT; t++) {
      size_t base = ((size_t)(b * TT + t) * SS + s) * DAUGP;
      Qa[base + 64 + j] = f2bf(corr[et * TT + t] * e);
      Qa[base + 80 + j] = 0;
    }
  } else {
    float dx = ((float)(s - en) - ce) / sig;
    unsigned short bv = f2bf(wgt * __expf(-0.5f * dx * dx));
    #pragma unroll
    for (int t = 0; t < TT; t++) {
      size_t base = ((size_t)(b * TT + t) * SS + s) * DAUGP;
      Ka[base + 64 + j] = bv;
      Ka[base + 80 + j] = 0;
    }
  }
}

// ---------------- k5: logits = Qa @ Ka^T (MFMA bf16) + mask ----------------------
__global__ __launch_bounds__(256) void k5_logits(
    const unsigned short* __restrict__ Qa, const unsigned short* __restrict__ Ka,
    const float* __restrict__ amask, float* __restrict__ out) {
  int bz = blockIdx.z; int b = bz >> 3;
  int n0 = blockIdx.x * 128, m0 = blockIdx.y * 128;
  int tid = threadIdx.x;
  if (n0 + 127 < m0) {
    // strictly below diagonal: write masked constant
    int r0 = tid >> 5, c4 = (tid & 31) * 4;
    float4 pv = *(const float4*)&amask[b * SS + n0 + c4];
    float4 o;
    o.x = (-(1.f - pv.x) * NEGV - NEGV) * 0.125f;
    o.y = (-(1.f - pv.y) * NEGV - NEGV) * 0.125f;
    o.z = (-(1.f - pv.z) * NEGV - NEGV) * 0.125f;
    o.w = (-(1.f - pv.w) * NEGV - NEGV) * 0.125f;
    for (int r = r0; r < 128; r += 8)
      *(float4*)&out[((size_t)bz * SS + m0 + r) * SS + n0 + c4] = o;
    return;
  }
  __shared__ unsigned short Qs[128 * 104];   // [m][kpad=104]
  __shared__ unsigned short Ks[128 * 104];   // [n][kpad=104]
  const unsigned short* Qrow = Qa + ((size_t)bz * SS + m0) * DAUGP;
  const unsigned short* Krow = Ka + ((size_t)bz * SS + n0) * DAUGP;
  #pragma unroll
  for (int it = 0; it < 6; it++) {
    int idx = tid + it * 256;                // 0..1535
    int r = idx / 12, seg = idx % 12;
    uint4 vq = *(const uint4*)(Qrow + (size_t)r * DAUGP + seg * 8);
    uint4 vk = *(const uint4*)(Krow + (size_t)r * DAUGP + seg * 8);
    *(uint4*)&Qs[r * 104 + seg * 8] = vq;
    *(uint4*)&Ks[r * 104 + seg * 8] = vk;
  }
  __syncthreads();
  int wave = tid >> 6, lane = tid & 63;
  int wr = wave >> 1, wc = wave & 1;
  int colL = lane & 15, quad = lane >> 4;
  f32x4 acc[4][4];
  #pragma unroll
  for (int i = 0; i < 4; i++)
    #pragma unroll
    for (int j = 0; j < 4; j++) { acc[i][j][0] = 0.f; acc[i][j][1] = 0.f; acc[i][j][2] = 0.f; acc[i][j][3] = 0.f; }
  #pragma unroll
  for (int ks = 0; ks < 3; ks++) {
    bf16x8 af[4], bf[4];
    #pragma unroll
    for (int tm = 0; tm < 4; tm++)
      af[tm] = *(const bf16x8*)&Qs[(wr * 64 + tm * 16 + colL) * 104 + ks * 32 + quad * 8];
    #pragma unroll
    for (int tn = 0; tn < 4; tn++)
      bf[tn] = *(const bf16x8*)&Ks[(wc * 64 + tn * 16 + colL) * 104 + ks * 32 + quad * 8];
    #pragma unroll
    for (int tm = 0; tm < 4; tm++)
      #pragma unroll
      for (int tn = 0; tn < 4; tn++)
        acc[tm][tn] = __builtin_amdgcn_mfma_f32_16x16x32_bf16(af[tm], bf[tn], acc[tm][tn], 0, 0, 0);
  }
  #pragma unroll
  for (int tn = 0; tn < 4; tn++) {
    int col = n0 + wc * 64 + tn * 16 + colL;
    float p = amask[b * SS + col];
    float negp = -(1.f - p) * NEGV;
    #pragma unroll
    for (int tm = 0; tm < 4; tm++) {
      int rbase = m0 + wr * 64 + tm * 16 + quad * 4;
      #pragma unroll
      for (int r = 0; r < 4; r++) {
        int m = rbase + r;
        float v = acc[tm][tn][r] * p + negp;
        if (col < m) v -= NEGV;
        out[((size_t)bz * SS + m) * SS + col] = v * 0.125f;
      }
    }
  }
}

extern "C" void kernel_launch(void* const* d_in, const int* in_sizes, int n_in,
                              void* d_out, int out_size, void* d_ws, size_t ws_size,
                              hipStream_t stream) {
  const float* hidden  = (const float*)d_in[0];
  const float* amask   = (const float*)d_in[1];
  const int*   spans   = (const int*)d_in[2];
  const float* W1      = (const float*)d_in[3];
  const float* a_src1  = (const float*)d_in[4];
  const float* a_dst1  = (const float*)d_in[5];
  const float* b1      = (const float*)d_in[6];
  const float* ln_g    = (const float*)d_in[7];
  const float* ln_b    = (const float*)d_in[8];
  const float* W2      = (const float*)d_in[9];
  const float* a_src2  = (const float*)d_in[10];
  const float* a_dst2  = (const float*)d_in[11];
  const float* b2      = (const float*)d_in[12];
  const float* dense_W = (const float*)d_in[13];
  const float* dense_b = (const float*)d_in[14];
  const float* gc      = (const float*)d_in[15];
  const float* gs      = (const float*)d_in[16];
  const float* gw      = (const float*)d_in[17];
  const float* corr    = (const float*)d_in[18];

  char* wsb = (char*)d_ws;
  unsigned short* hbf  = (unsigned short*)wsb;                wsb += (size_t)BB * SS * HH * 2;          // 12.6 MB
  unsigned short* WtopT= (unsigned short*)wsb;                wsb += (size_t)CDIM * HH * 2;             // 1.57 MB
  unsigned short* Qa   = (unsigned short*)wsb;                wsb += (size_t)BB * TT * SS * DAUGP * 2;  // 12.6 MB
  unsigned short* Ka   = (unsigned short*)wsb;                wsb += (size_t)BB * TT * SS * DAUGP * 2;  // 12.6 MB
  float* nodes         = (float*)wsb;                         wsb += (size_t)BB * NNODES * HH * 4;
  float* cover         = (float*)wsb;                         wsb += (size_t)BB * SS * 4;
  float* E2            = (float*)wsb;                         wsb += (size_t)BB * CDIM * 4;
  float* enhg          = (float*)wsb;                         wsb += (size_t)BB * GDIM * 4;
  float* part          = (float*)wsb;                         wsb += (size_t)BB * 16 * HH * 4;
  float* outp = (float*)d_out;

  kc1b_cvt_partial<<<dim3(16, BB), 256, 0, stream>>>(hidden, hbf, part);
  kc2_cvt_wtop<<<dim3(HH / 32, CDIM / 32), 256, 0, stream>>>(dense_W, WtopT);
  k1a_spans<<<dim3(KSP, BB), 256, 0, stream>>>(hidden, spans, nodes, cover);
  k4g_gauss<<<(BB * SS) / 8, 256, 0, stream>>>(spans, corr, gc, gs, gw, Qa, Ka);
  k2_gat<<<BB, 512, 0, stream>>>(part, nodes, spans, W1, a_src1, a_dst1, b1, ln_g, ln_b,
                                 W2, a_src2, a_dst2, b2, enhg);
  k2b_e2<<<dim3(CDIM / 256, BB), 256, 0, stream>>>(enhg, dense_W, E2);
  k3_dense<<<dim3(CDIM / 128, (BB * SS) / 128), 256, 0, stream>>>(hbf, WtopT, dense_b,
                                                                  cover, E2, Qa, Ka);
  k5_logits<<<dim3(8, 8, BB * TT), 256, 0, stream>>>(Qa, Ka, amask, outp);
}